// Round 4
// baseline (201.625 us; speedup 1.0000x reference)
//
#include <hip/hip_runtime.h>
#include <math.h>

#define GROUPS 10
#define INPUTS 6
#define COLS (GROUPS * INPUTS)   // 60
#define EPSV 1e-4f

// ---- staged K1 config: 1 wave per block, 64-row tiles ----
#define TNT 64                    // threads per block (1 wave)
#define TROWS 64                  // rows per tile
#define TF4 (TROWS * 15)          // 960 float4 per tile (15,360 B LDS)
#define K1B 2560                  // 10 blocks/CU on 256 CUs (LDS-limited)

// ---- generic fallback config ----
#define NB1 2048
#define NT 256

// pack two f32 -> two bf16 (round to nearest even) in one uint
__device__ inline unsigned bf16pair(float a, float b) {
    unsigned ua = __float_as_uint(a);
    unsigned ub = __float_as_uint(b);
    ua += 0x7fffu + ((ua >> 16) & 1u);
    ub += 0x7fffu + ((ub >> 16) & 1u);
    return (ua >> 16) | (ub & 0xffff0000u);
}

// ===========================================================================
// K1: coalesced global->LDS tile, each lane computes one row, y stored bf16.
// Per-block partials; LAST block reduces partials -> ss (scale/shift).
// Deterministic: fixed-order reductions; atomic only elects a leader.
// ===========================================================================
__global__ __launch_bounds__(TNT) void k1_staged(
    const float* __restrict__ in,      // [B, 60]
    const float* __restrict__ Wp,      // [10, 6]
    const float* __restrict__ bp,      // [10]
    const float* __restrict__ gamma,   // [10]
    const float* __restrict__ beta,    // [10]
    unsigned* __restrict__ y16,        // [B*10/2] uints (bf16 pairs)
    float* __restrict__ partials,      // [grid, 20]
    float* __restrict__ ss,            // [20] scale/shift out
    unsigned* __restrict__ counter,    // [1], zeroed before launch
    int ntiles, float invB)
{
    __shared__ float4 tile[TF4];       // 15,360 B
    __shared__ bool amLast;
    const int tid = threadIdx.x;
    const int nblocks = gridDim.x;

    float Wr[COLS];
#pragma unroll
    for (int j = 0; j < COLS; ++j) Wr[j] = Wp[j];
    float br[GROUPS];
#pragma unroll
    for (int g = 0; g < GROUPS; ++g) br[g] = bp[g];

    float s[GROUPS], sq[GROUPS];
#pragma unroll
    for (int g = 0; g < GROUPS; ++g) { s[g] = 0.f; sq[g] = 0.f; }

    for (int t = blockIdx.x; t < ntiles; t += nblocks) {
        const float4* src = reinterpret_cast<const float4*>(in) + (size_t)t * TF4;

        __syncthreads();   // previous iteration's LDS reads must finish
#pragma unroll
        for (int j = 0; j < 15; ++j)
            tile[j * TNT + tid] = src[j * TNT + tid];   // 1 KB contiguous/instr
        __syncthreads();

        const float* x = reinterpret_cast<const float*>(&tile[tid * 15]);
        float y[GROUPS];
#pragma unroll
        for (int g = 0; g < GROUPS; ++g) {
            float acc = br[g];
#pragma unroll
            for (int i = 0; i < INPUTS; ++i)
                acc = fmaf(x[g * INPUTS + i], Wr[g * INPUTS + i], acc);
            y[g] = acc;
            s[g] += acc;
            sq[g] = fmaf(acc, acc, sq[g]);
        }

        const size_t r = (size_t)t * TROWS + tid;
        unsigned* yo = y16 + r * (GROUPS / 2);
#pragma unroll
        for (int j = 0; j < 5; ++j)
            yo[j] = bf16pair(y[2 * j], y[2 * j + 1]);
    }

    // block (= wave) reduction
#pragma unroll
    for (int off = 32; off > 0; off >>= 1) {
#pragma unroll
        for (int g = 0; g < GROUPS; ++g) {
            s[g]  += __shfl_down(s[g],  off, 64);
            sq[g] += __shfl_down(sq[g], off, 64);
        }
    }
    if (tid == 0) {
        float* p = partials + (size_t)blockIdx.x * (2 * GROUPS);
#pragma unroll
        for (int g = 0; g < GROUPS; ++g) {
            p[g]          = s[g];
            p[GROUPS + g] = sq[g];
        }
        __threadfence();                       // publish partials
        unsigned ticket = atomicAdd(counter, 1u);
        amLast = (ticket == (unsigned)(nblocks - 1));
    }
    __syncthreads();

    if (amLast) {
        __threadfence();                       // acquire all partials
        float acc[2 * GROUPS];
#pragma unroll
        for (int j = 0; j < 2 * GROUPS; ++j) acc[j] = 0.f;
        for (int b = tid; b < nblocks; b += TNT) {
            const float* p = partials + (size_t)b * (2 * GROUPS);
#pragma unroll
            for (int j = 0; j < 2 * GROUPS; ++j) acc[j] += p[j];
        }
#pragma unroll
        for (int off = 32; off > 0; off >>= 1) {
#pragma unroll
            for (int j = 0; j < 2 * GROUPS; ++j)
                acc[j] += __shfl_down(acc[j], off, 64);
        }
        if (tid == 0) {
#pragma unroll
            for (int g = 0; g < GROUPS; ++g) {
                float mean = acc[g] * invB;
                float var  = acc[GROUPS + g] * invB - mean * mean;  // biased
                float sc   = gamma[g] * rsqrtf(var + EPSV);
                ss[g]          = sc;
                ss[GROUPS + g] = beta[g] - mean * sc;
            }
        }
    }
}

// ===========================================================================
// K3: read bf16 y (uint4 = 8 elems), normalize, write f32 out.
// ===========================================================================
__global__ __launch_bounds__(NT) void k3_normalize_bf16(
    const uint4* __restrict__ y8,      // n8 uint4s
    const float* __restrict__ ss,
    float4* __restrict__ out4,         // 2*n8 float4s
    int n8)
{
    __shared__ float sc[GROUPS], sh[GROUPS];
    if (threadIdx.x < GROUPS) {
        sc[threadIdx.x] = ss[threadIdx.x];
        sh[threadIdx.x] = ss[GROUPS + threadIdx.x];
    }
    __syncthreads();

    int gid = blockIdx.x * NT + threadIdx.x;
    int stride = gridDim.x * NT;
    for (int q = gid; q < n8; q += stride) {
        uint4 v = y8[q];
        float e[8];
        e[0] = __uint_as_float(v.x << 16);
        e[1] = __uint_as_float(v.x & 0xffff0000u);
        e[2] = __uint_as_float(v.y << 16);
        e[3] = __uint_as_float(v.y & 0xffff0000u);
        e[4] = __uint_as_float(v.z << 16);
        e[5] = __uint_as_float(v.z & 0xffff0000u);
        e[6] = __uint_as_float(v.w << 16);
        e[7] = __uint_as_float(v.w & 0xffff0000u);

        const int e0 = (q * 8) % GROUPS;
        float r[8];
#pragma unroll
        for (int k = 0; k < 8; ++k) {
            int g = e0 + k;               // <= 16
            if (g >= GROUPS) g -= GROUPS;
            r[k] = fmaf(e[k], sc[g], sh[g]);
        }
        out4[2 * q]     = make_float4(r[0], r[1], r[2], r[3]);
        out4[2 * q + 1] = make_float4(r[4], r[5], r[6], r[7]);
    }
}

// ===========================================================================
// Generic fallback path (f32 y, separate K2) — proven correct.
// ===========================================================================
__global__ __launch_bounds__(NT) void k1_compute(
    const float* __restrict__ in, const float* __restrict__ Wp,
    const float* __restrict__ bp, float* __restrict__ y_out,
    float* __restrict__ partials, int B)
{
    const int tid = threadIdx.x;
    const int gid = blockIdx.x * NT + tid;
    const int stride = gridDim.x * NT;

    float Wr[COLS];
#pragma unroll
    for (int j = 0; j < COLS; ++j) Wr[j] = Wp[j];
    float br[GROUPS];
#pragma unroll
    for (int g = 0; g < GROUPS; ++g) br[g] = bp[g];

    float s[GROUPS], sq[GROUPS];
#pragma unroll
    for (int g = 0; g < GROUPS; ++g) { s[g] = 0.f; sq[g] = 0.f; }

    for (int r = gid; r < B; r += stride) {
        const float4* row4 = reinterpret_cast<const float4*>(in + (size_t)r * COLS);
        float4 v[15];
#pragma unroll
        for (int j = 0; j < 15; ++j) v[j] = row4[j];
        const float* x = reinterpret_cast<const float*>(v);
        float y[GROUPS];
#pragma unroll
        for (int g = 0; g < GROUPS; ++g) {
            float acc = br[g];
#pragma unroll
            for (int i = 0; i < INPUTS; ++i)
                acc = fmaf(x[g * INPUTS + i], Wr[g * INPUTS + i], acc);
            y[g] = acc;
            s[g] += acc;
            sq[g] = fmaf(acc, acc, sq[g]);
        }
        float2* yo = reinterpret_cast<float2*>(y_out + (size_t)r * GROUPS);
#pragma unroll
        for (int j = 0; j < 5; ++j) yo[j] = make_float2(y[2 * j], y[2 * j + 1]);
    }

#pragma unroll
    for (int off = 32; off > 0; off >>= 1) {
#pragma unroll
        for (int g = 0; g < GROUPS; ++g) {
            s[g]  += __shfl_down(s[g],  off, 64);
            sq[g] += __shfl_down(sq[g], off, 64);
        }
    }
    __shared__ float ls[NT / 64][2 * GROUPS];
    const int lane = tid & 63;
    const int wid  = tid >> 6;
    if (lane == 0) {
#pragma unroll
        for (int g = 0; g < GROUPS; ++g) {
            ls[wid][g]          = s[g];
            ls[wid][GROUPS + g] = sq[g];
        }
    }
    __syncthreads();
    if (tid < 2 * GROUPS) {
        float t = ls[0][tid] + ls[1][tid] + ls[2][tid] + ls[3][tid];
        partials[(size_t)blockIdx.x * (2 * GROUPS) + tid] = t;
    }
}

__global__ __launch_bounds__(NT) void k2_finalize(
    const float* __restrict__ partials, int nblocks,
    const float* __restrict__ gamma, const float* __restrict__ beta,
    float* __restrict__ ss, float invB)
{
    const int tid = threadIdx.x;
    float acc[2 * GROUPS];
#pragma unroll
    for (int j = 0; j < 2 * GROUPS; ++j) acc[j] = 0.f;
    for (int blk = tid; blk < nblocks; blk += NT) {
        const float* p = partials + (size_t)blk * (2 * GROUPS);
#pragma unroll
        for (int j = 0; j < 2 * GROUPS; ++j) acc[j] += p[j];
    }
#pragma unroll
    for (int off = 32; off > 0; off >>= 1) {
#pragma unroll
        for (int j = 0; j < 2 * GROUPS; ++j)
            acc[j] += __shfl_down(acc[j], off, 64);
    }
    __shared__ float ls[NT / 64][2 * GROUPS];
    const int lane = tid & 63;
    const int wid  = tid >> 6;
    if (lane == 0) {
#pragma unroll
        for (int j = 0; j < 2 * GROUPS; ++j) ls[wid][j] = acc[j];
    }
    __syncthreads();
    if (tid < GROUPS) {
        float sum  = ls[0][tid] + ls[1][tid] + ls[2][tid] + ls[3][tid];
        float sumq = ls[0][GROUPS + tid] + ls[1][GROUPS + tid] +
                     ls[2][GROUPS + tid] + ls[3][GROUPS + tid];
        float mean = sum * invB;
        float var  = sumq * invB - mean * mean;
        float sc   = gamma[tid] * rsqrtf(var + EPSV);
        ss[tid]          = sc;
        ss[GROUPS + tid] = beta[tid] - mean * sc;
    }
}

__global__ __launch_bounds__(NT) void k3_normalize(
    const float4* __restrict__ y4, const float* __restrict__ ss,
    float4* __restrict__ out4, int n4)
{
    __shared__ float sc[GROUPS], sh[GROUPS];
    if (threadIdx.x < GROUPS) {
        sc[threadIdx.x] = ss[threadIdx.x];
        sh[threadIdx.x] = ss[GROUPS + threadIdx.x];
    }
    __syncthreads();
    int gid = blockIdx.x * NT + threadIdx.x;
    int stride = gridDim.x * NT;
    for (int q = gid; q < n4; q += stride) {
        float4 v = y4[q];
        int g0 = (q * 4) % GROUPS;
        int g1 = g0 + 1; if (g1 >= GROUPS) g1 -= GROUPS;
        int g2 = g1 + 1; if (g2 >= GROUPS) g2 -= GROUPS;
        int g3 = g2 + 1; if (g3 >= GROUPS) g3 -= GROUPS;
        v.x = fmaf(v.x, sc[g0], sh[g0]);
        v.y = fmaf(v.y, sc[g1], sh[g1]);
        v.z = fmaf(v.z, sc[g2], sh[g2]);
        v.w = fmaf(v.w, sc[g3], sh[g3]);
        out4[q] = v;
    }
}

extern "C" void kernel_launch(void* const* d_in, const int* in_sizes, int n_in,
                              void* d_out, int out_size, void* d_ws, size_t ws_size,
                              hipStream_t stream)
{
    const float* in    = (const float*)d_in[0];
    const float* W     = (const float*)d_in[1];
    const float* bias  = (const float*)d_in[2];
    const float* gamma = (const float*)d_in[3];
    const float* beta  = (const float*)d_in[4];
    float* out = (float*)d_out;

    const int B = in_sizes[0] / COLS;      // 1048576
    char* ws = (char*)d_ws;

    if ((B % TROWS) == 0) {
        // ---- fast path: bf16 y + last-block finalize ----
        const int ntiles = B / TROWS;
        const int nb1    = (ntiles < K1B) ? ntiles : K1B;

        const size_t yBytes    = (size_t)B * GROUPS * 2;            // bf16
        const size_t partBytes = (size_t)nb1 * 2 * GROUPS * sizeof(float);
        size_t off = 0;
        unsigned* y16   = (unsigned*)(ws + off); off += yBytes;
        off = (off + 255) & ~(size_t)255;
        float* partials = (float*)(ws + off);    off += partBytes;
        float* ss       = (float*)(ws + off);    off += 2 * GROUPS * sizeof(float);
        unsigned* ctr   = (unsigned*)(ws + off); off += sizeof(unsigned);

        if (ws_size >= off) {
            hipMemsetAsync(ctr, 0, sizeof(unsigned), stream);
            k1_staged<<<nb1, TNT, 0, stream>>>(in, W, bias, gamma, beta,
                                               y16, partials, ss, ctr,
                                               ntiles, 1.0f / (float)B);
            const int n8 = (B * GROUPS) / 8;   // B%64==0 -> divisible
            k3_normalize_bf16<<<2048, NT, 0, stream>>>(
                (const uint4*)y16, ss, (float4*)out, n8);
            return;
        }
    }

    // ---- fallback: f32 y, 3-kernel path ----
    {
        float* fws = (float*)d_ws;
        const size_t yFloats    = (size_t)B * GROUPS;
        const size_t partFloats = (size_t)NB1 * 2 * GROUPS;
        float* y_ws     = fws;
        float* partials = fws + yFloats;
        float* ss       = partials + partFloats;
        k1_compute<<<NB1, NT, 0, stream>>>(in, W, bias, y_ws, partials, B);
        k2_finalize<<<1, NT, 0, stream>>>(partials, NB1, gamma, beta, ss, 1.0f / (float)B);
        const int n4 = (B * GROUPS) / 4;
        k3_normalize<<<2048, NT, 0, stream>>>((const float4*)y_ws, ss, (float4*)out, n4);
    }
}

// Round 5
// 68.642 us; speedup vs baseline: 2.9373x; 2.9373x over previous
//
#include <hip/hip_runtime.h>
#include <math.h>

#define GROUPS 10
#define INPUTS 6
#define COLS (GROUPS * INPUTS)   // 60
#define EPSV 1e-4f

// ---- staged K1 config: 1 wave per block, 64-row tiles ----
#define TNT 64                    // threads per block (1 wave)
#define TROWS 64                  // rows per tile
#define TF4 (TROWS * 15)          // 960 float4 per tile (15,360 B LDS)
#define K1B 2560                  // 10 blocks/CU on 256 CUs (LDS-limited)

// ---- generic fallback config ----
#define NB1 2048
#define NT 256

// pack two f32 -> two bf16 (round to nearest even) in one uint
__device__ inline unsigned bf16pair(float a, float b) {
    unsigned ua = __float_as_uint(a);
    unsigned ub = __float_as_uint(b);
    ua += 0x7fffu + ((ua >> 16) & 1u);
    ub += 0x7fffu + ((ub >> 16) & 1u);
    return (ua >> 16) | (ub & 0xffff0000u);
}

// ===========================================================================
// K1: coalesced global->LDS tile, each lane computes one row, y stored bf16.
// Per-block partials[20]. NO fences/atomics (round-4 lesson: device-scope
// release per block serialized L2 writebacks and cost 160 µs).
// ===========================================================================
__global__ __launch_bounds__(TNT) void k1_staged(
    const float* __restrict__ in,      // [B, 60]
    const float* __restrict__ Wp,      // [10, 6]
    const float* __restrict__ bp,      // [10]
    unsigned* __restrict__ y16,        // [B*10/2] uints (bf16 pairs)
    float* __restrict__ partials,      // [grid, 20]
    int ntiles)
{
    __shared__ float4 tile[TF4];       // 15,360 B
    const int tid = threadIdx.x;

    float Wr[COLS];
#pragma unroll
    for (int j = 0; j < COLS; ++j) Wr[j] = Wp[j];
    float br[GROUPS];
#pragma unroll
    for (int g = 0; g < GROUPS; ++g) br[g] = bp[g];

    float s[GROUPS], sq[GROUPS];
#pragma unroll
    for (int g = 0; g < GROUPS; ++g) { s[g] = 0.f; sq[g] = 0.f; }

    for (int t = blockIdx.x; t < ntiles; t += gridDim.x) {
        const float4* src = reinterpret_cast<const float4*>(in) + (size_t)t * TF4;

        __syncthreads();   // previous iteration's LDS reads must finish
#pragma unroll
        for (int j = 0; j < 15; ++j)
            tile[j * TNT + tid] = src[j * TNT + tid];   // 1 KB contiguous/instr
        __syncthreads();

        const float* x = reinterpret_cast<const float*>(&tile[tid * 15]);
        float y[GROUPS];
#pragma unroll
        for (int g = 0; g < GROUPS; ++g) {
            float acc = br[g];
#pragma unroll
            for (int i = 0; i < INPUTS; ++i)
                acc = fmaf(x[g * INPUTS + i], Wr[g * INPUTS + i], acc);
            y[g] = acc;
            s[g] += acc;
            sq[g] = fmaf(acc, acc, sq[g]);
        }

        const size_t r = (size_t)t * TROWS + tid;
        unsigned* yo = y16 + r * (GROUPS / 2);
#pragma unroll
        for (int j = 0; j < 5; ++j)
            yo[j] = bf16pair(y[2 * j], y[2 * j + 1]);
    }

    // block (= wave) shuffle reduction, fixed order -> deterministic
#pragma unroll
    for (int off = 32; off > 0; off >>= 1) {
#pragma unroll
        for (int g = 0; g < GROUPS; ++g) {
            s[g]  += __shfl_down(s[g],  off, 64);
            sq[g] += __shfl_down(sq[g], off, 64);
        }
    }
    if (tid == 0) {
        float* p = partials + (size_t)blockIdx.x * (2 * GROUPS);
#pragma unroll
        for (int g = 0; g < GROUPS; ++g) {
            p[g]          = s[g];
            p[GROUPS + g] = sq[g];
        }
    }
}

// ===========================================================================
// K2: reduce per-block partials -> scale/shift. Single block, deterministic.
// ===========================================================================
__global__ __launch_bounds__(NT) void k2_finalize(
    const float* __restrict__ partials, int nblocks,
    const float* __restrict__ gamma, const float* __restrict__ beta,
    float* __restrict__ ss, float invB)
{
    const int tid = threadIdx.x;
    float acc[2 * GROUPS];
#pragma unroll
    for (int j = 0; j < 2 * GROUPS; ++j) acc[j] = 0.f;
    for (int blk = tid; blk < nblocks; blk += NT) {
        const float* p = partials + (size_t)blk * (2 * GROUPS);
#pragma unroll
        for (int j = 0; j < 2 * GROUPS; ++j) acc[j] += p[j];
    }
#pragma unroll
    for (int off = 32; off > 0; off >>= 1) {
#pragma unroll
        for (int j = 0; j < 2 * GROUPS; ++j)
            acc[j] += __shfl_down(acc[j], off, 64);
    }
    __shared__ float ls[NT / 64][2 * GROUPS];
    const int lane = tid & 63;
    const int wid  = tid >> 6;
    if (lane == 0) {
#pragma unroll
        for (int j = 0; j < 2 * GROUPS; ++j) ls[wid][j] = acc[j];
    }
    __syncthreads();
    if (tid < GROUPS) {
        float sum  = ls[0][tid] + ls[1][tid] + ls[2][tid] + ls[3][tid];
        float sumq = ls[0][GROUPS + tid] + ls[1][GROUPS + tid] +
                     ls[2][GROUPS + tid] + ls[3][GROUPS + tid];
        float mean = sum * invB;
        float var  = sumq * invB - mean * mean;   // biased variance
        float sc   = gamma[tid] * rsqrtf(var + EPSV);
        ss[tid]          = sc;
        ss[GROUPS + tid] = beta[tid] - mean * sc;
    }
}

// ===========================================================================
// K3: read bf16 y (uint4 = 8 elems), normalize, write f32 out.
// ===========================================================================
__global__ __launch_bounds__(NT) void k3_normalize_bf16(
    const uint4* __restrict__ y8,      // n8 uint4s
    const float* __restrict__ ss,
    float4* __restrict__ out4,         // 2*n8 float4s
    int n8)
{
    __shared__ float sc[GROUPS], sh[GROUPS];
    if (threadIdx.x < GROUPS) {
        sc[threadIdx.x] = ss[threadIdx.x];
        sh[threadIdx.x] = ss[GROUPS + threadIdx.x];
    }
    __syncthreads();

    int gid = blockIdx.x * NT + threadIdx.x;
    int stride = gridDim.x * NT;
    for (int q = gid; q < n8; q += stride) {
        uint4 v = y8[q];
        float e[8];
        e[0] = __uint_as_float(v.x << 16);
        e[1] = __uint_as_float(v.x & 0xffff0000u);
        e[2] = __uint_as_float(v.y << 16);
        e[3] = __uint_as_float(v.y & 0xffff0000u);
        e[4] = __uint_as_float(v.z << 16);
        e[5] = __uint_as_float(v.z & 0xffff0000u);
        e[6] = __uint_as_float(v.w << 16);
        e[7] = __uint_as_float(v.w & 0xffff0000u);

        const int e0 = (q * 8) % GROUPS;
        float r[8];
#pragma unroll
        for (int k = 0; k < 8; ++k) {
            int g = e0 + k;
            if (g >= GROUPS) g -= GROUPS;
            r[k] = fmaf(e[k], sc[g], sh[g]);
        }
        out4[2 * q]     = make_float4(r[0], r[1], r[2], r[3]);
        out4[2 * q + 1] = make_float4(r[4], r[5], r[6], r[7]);
    }
}

// ===========================================================================
// Generic fallback path (f32 y) for shapes with B % 64 != 0.
// ===========================================================================
__global__ __launch_bounds__(NT) void k1_compute(
    const float* __restrict__ in, const float* __restrict__ Wp,
    const float* __restrict__ bp, float* __restrict__ y_out,
    float* __restrict__ partials, int B)
{
    const int tid = threadIdx.x;
    const int gid = blockIdx.x * NT + tid;
    const int stride = gridDim.x * NT;

    float Wr[COLS];
#pragma unroll
    for (int j = 0; j < COLS; ++j) Wr[j] = Wp[j];
    float br[GROUPS];
#pragma unroll
    for (int g = 0; g < GROUPS; ++g) br[g] = bp[g];

    float s[GROUPS], sq[GROUPS];
#pragma unroll
    for (int g = 0; g < GROUPS; ++g) { s[g] = 0.f; sq[g] = 0.f; }

    for (int r = gid; r < B; r += stride) {
        const float4* row4 = reinterpret_cast<const float4*>(in + (size_t)r * COLS);
        float4 v[15];
#pragma unroll
        for (int j = 0; j < 15; ++j) v[j] = row4[j];
        const float* x = reinterpret_cast<const float*>(v);
        float y[GROUPS];
#pragma unroll
        for (int g = 0; g < GROUPS; ++g) {
            float acc = br[g];
#pragma unroll
            for (int i = 0; i < INPUTS; ++i)
                acc = fmaf(x[g * INPUTS + i], Wr[g * INPUTS + i], acc);
            y[g] = acc;
            s[g] += acc;
            sq[g] = fmaf(acc, acc, sq[g]);
        }
        float2* yo = reinterpret_cast<float2*>(y_out + (size_t)r * GROUPS);
#pragma unroll
        for (int j = 0; j < 5; ++j) yo[j] = make_float2(y[2 * j], y[2 * j + 1]);
    }

#pragma unroll
    for (int off = 32; off > 0; off >>= 1) {
#pragma unroll
        for (int g = 0; g < GROUPS; ++g) {
            s[g]  += __shfl_down(s[g],  off, 64);
            sq[g] += __shfl_down(sq[g], off, 64);
        }
    }
    __shared__ float ls[NT / 64][2 * GROUPS];
    const int lane = tid & 63;
    const int wid  = tid >> 6;
    if (lane == 0) {
#pragma unroll
        for (int g = 0; g < GROUPS; ++g) {
            ls[wid][g]          = s[g];
            ls[wid][GROUPS + g] = sq[g];
        }
    }
    __syncthreads();
    if (tid < 2 * GROUPS) {
        float t = ls[0][tid] + ls[1][tid] + ls[2][tid] + ls[3][tid];
        partials[(size_t)blockIdx.x * (2 * GROUPS) + tid] = t;
    }
}

__global__ __launch_bounds__(NT) void k3_normalize(
    const float4* __restrict__ y4, const float* __restrict__ ss,
    float4* __restrict__ out4, int n4)
{
    __shared__ float sc[GROUPS], sh[GROUPS];
    if (threadIdx.x < GROUPS) {
        sc[threadIdx.x] = ss[threadIdx.x];
        sh[threadIdx.x] = ss[GROUPS + threadIdx.x];
    }
    __syncthreads();
    int gid = blockIdx.x * NT + threadIdx.x;
    int stride = gridDim.x * NT;
    for (int q = gid; q < n4; q += stride) {
        float4 v = y4[q];
        int g0 = (q * 4) % GROUPS;
        int g1 = g0 + 1; if (g1 >= GROUPS) g1 -= GROUPS;
        int g2 = g1 + 1; if (g2 >= GROUPS) g2 -= GROUPS;
        int g3 = g2 + 1; if (g3 >= GROUPS) g3 -= GROUPS;
        v.x = fmaf(v.x, sc[g0], sh[g0]);
        v.y = fmaf(v.y, sc[g1], sh[g1]);
        v.z = fmaf(v.z, sc[g2], sh[g2]);
        v.w = fmaf(v.w, sc[g3], sh[g3]);
        out4[q] = v;
    }
}

extern "C" void kernel_launch(void* const* d_in, const int* in_sizes, int n_in,
                              void* d_out, int out_size, void* d_ws, size_t ws_size,
                              hipStream_t stream)
{
    const float* in    = (const float*)d_in[0];
    const float* W     = (const float*)d_in[1];
    const float* bias  = (const float*)d_in[2];
    const float* gamma = (const float*)d_in[3];
    const float* beta  = (const float*)d_in[4];
    float* out = (float*)d_out;

    const int B = in_sizes[0] / COLS;      // 1048576
    char* ws = (char*)d_ws;

    if ((B % TROWS) == 0) {
        // ---- fast path: staged K1 + bf16 y + tiny K2 + bf16 K3 ----
        const int ntiles = B / TROWS;
        const int nb1    = (ntiles < K1B) ? ntiles : K1B;

        const size_t yBytes    = (size_t)B * GROUPS * 2;            // bf16
        const size_t partBytes = (size_t)nb1 * 2 * GROUPS * sizeof(float);
        size_t off = 0;
        unsigned* y16   = (unsigned*)(ws + off); off += yBytes;
        off = (off + 255) & ~(size_t)255;
        float* partials = (float*)(ws + off);    off += partBytes;
        float* ss       = (float*)(ws + off);    off += 2 * GROUPS * sizeof(float);

        if (ws_size >= off) {
            k1_staged<<<nb1, TNT, 0, stream>>>(in, W, bias, y16, partials, ntiles);
            k2_finalize<<<1, NT, 0, stream>>>(partials, nb1, gamma, beta, ss,
                                              1.0f / (float)B);
            const int n8 = (B * GROUPS) / 8;   // B%64==0 -> divisible
            k3_normalize_bf16<<<2048, NT, 0, stream>>>(
                (const uint4*)y16, ss, (float4*)out, n8);
            return;
        }
    }

    // ---- fallback: f32 y, 3-kernel path ----
    {
        float* fws = (float*)d_ws;
        const size_t yFloats    = (size_t)B * GROUPS;
        const size_t partFloats = (size_t)NB1 * 2 * GROUPS;
        float* y_ws     = fws;
        float* partials = fws + yFloats;
        float* ss       = partials + partFloats;
        k1_compute<<<NB1, NT, 0, stream>>>(in, W, bias, y_ws, partials, B);
        k2_finalize<<<1, NT, 0, stream>>>(partials, NB1, gamma, beta, ss, 1.0f / (float)B);
        const int n4 = (B * GROUPS) / 4;
        k3_normalize<<<2048, NT, 0, stream>>>((const float4*)y_ws, ss, (float4*)out, n4);
    }
}